// Round 3
// baseline (3128.390 us; speedup 1.0000x reference)
//
#include <hip/hip_runtime.h>
#include <hip/hip_bf16.h>

// PixelContrastLossOnlyNeg on MI355X.
// feats [16,256,128,128] f32, queue [256,256] f32, labels [262144,256] i32 -> scalar f32.
// Fused bf16-MFMA GEMM (N=262144, M=256, K=256) + masked-exp reduction.
// Memory floor: feats 256MB + labels 256MB = 512MB -> ~81us @ 6.3TB/s.
//
// v3: persistent pixel-split streaming. v1/v2 both pinned at ~185us with all
// pipes <25% busy: burst-load phases + FIFO vmcnt semantics left waves with
// loads in flight only ~25% of the time. v3 makes every wave stream
// continuously: queue lives in LDS (128KB, staged once -> A-frags on lgkm,
// never touching vmcnt); each wave owns 16-pixel tiles x all 256 classes, so
// B-fragments are lane-private (global->reg->pack, no LDS) and softmax sums
// finish in-wave (no barriers, no cross-wave reduce). feats/labels issue in
// strict FIFO pipeline order across tiles (counted vmcnt, never drained).

typedef __bf16 bf16x8 __attribute__((ext_vector_type(8)));
typedef float floatx4 __attribute__((ext_vector_type(4)));

union BFrag {
  unsigned int u32[4];
  uint4 v;
  bf16x8 bf;
};

// Pack two f32 -> two bf16 (round-half-up; bias ~2^-17 rel, irrelevant here).
__device__ __forceinline__ unsigned int pack_bf2(float a, float b) {
  unsigned int ua = __float_as_uint(a) + 0x8000u;
  unsigned int ub = __float_as_uint(b) + 0x8000u;
  return (ua >> 16) | (ub & 0xffff0000u);
}

// ---------------------------------------------------------------------------
// k0: queue f32 -> bf16 * (log2e/T), stored pre-swizzled in A-fragment lane
// order: tile t = m16*8 + ks, lane L holds A[m=m16*16+(L&15)][k=ks*32+(L>>4)*8+j],
// j=0..7 -> 16B at (t*64+L)*16. Folding log2(e) puts MFMA output in exp2
// domain: exp(logit/T) == exp2(acc). Also zeroes the global accumulators.
// ---------------------------------------------------------------------------
__global__ void qprep(const float* __restrict__ queue,
                      unsigned short* __restrict__ qs,
                      float* __restrict__ accum) {
  const int gt = blockIdx.x * 256 + threadIdx.x;  // 0..8191
  const int t = gt >> 6;
  const int lane = gt & 63;
  const int m = ((t >> 3) << 4) | (lane & 15);
  const int k0 = ((t & 7) << 5) | ((lane >> 4) << 3);
  const float* qr = queue + m * 256 + k0;
  const float SCALE = 20.6099291556f;  // (1/0.07) * log2(e) folded into Q
  BFrag u;
#pragma unroll
  for (int j = 0; j < 4; ++j)
    u.u32[j] = pack_bf2(qr[2 * j] * SCALE, qr[2 * j + 1] * SCALE);
  *(uint4*)(qs + (size_t)gt * 8) = u.v;
  if (gt == 0) { accum[0] = 0.0f; accum[1] = 0.0f; }
}

// ---------------------------------------------------------------------------
// k1: persistent main kernel. 256 blocks (1 per CU, LDS-capped), 512 threads
// (8 waves). Wave (bx,w) owns pixels [bx*1024 + w*128, +128) as 8 tiles of 16.
// Per tile: pack 64 feats dwords -> 8 bf16x8 B-frags (lane-private);
// 4 class-chunks x 8 ks x {4 ds_read_b128 A-frag, 4 MFMA}; epilogue in exp2
// domain with labels prefetched 1+ chunk ahead. Zero barriers after prologue.
// ---------------------------------------------------------------------------
__global__ __launch_bounds__(512, 2) void pcl_main(
    const float* __restrict__ feats,
    const int* __restrict__ labels,
    const unsigned short* __restrict__ qs,
    float* __restrict__ accum) {
  __shared__ uint4 AF[8192];  // 128 KB: full swizzled queue, tile-lane-major

  const int tid = threadIdx.x;
  const int w = tid >> 6;
  const int lane = tid & 63;
  const int qd = lane >> 4;   // quad 0..3
  const int s = lane & 15;

  // ---- stage queue -> LDS (once; read-only afterwards) ----
  {
    const uint4* q4 = (const uint4*)qs;
#pragma unroll
    for (int i = 0; i < 16; ++i)
      AF[(i << 9) + tid] = q4[(i << 9) + tid];
  }

  const int wave_px = blockIdx.x * 1024 + (w << 7);  // + t*16 + s

  float FA[32], FB[32];
  int4 labP[4], lab1[4], lab2[4], lab3[4];

  // ---- prologue: issue tile-0 feats (both halves) + labels chunk0 ----
  {
    const int p0 = wave_px;
    const float* fb = feats + ((size_t)(p0 >> 14) << 22) + (p0 & 16383) + s;
#pragma unroll
    for (int i = 0; i < 32; ++i) {  // ks 0..3: k = 32*(i>>3) + 8*qd + (i&7)
      const int k = ((i >> 3) << 5) + (qd << 3) + (i & 7);
      FA[i] = fb[(size_t)k << 14];
    }
#pragma unroll
    for (int i = 0; i < 32; ++i) {  // ks 4..7
      const int k = 128 + ((i >> 3) << 5) + (qd << 3) + (i & 7);
      FB[i] = fb[(size_t)k << 14];
    }
    const int* lp = labels + (((size_t)p0 + s) << 8) + (qd << 2);
#pragma unroll
    for (int mt = 0; mt < 4; ++mt)
      labP[mt] = *(const int4*)(lp + (mt << 4));
  }

  __syncthreads();  // AF visible to all waves (single full drain, prologue only)

  float loss_acc = 0.0f, cnt_acc = 0.0f;

  // chunk C: classes [C*64, C*64+64); LB = labels for this chunk.
#define DO_CHUNK(C, LB)                                                       \
  do {                                                                        \
    floatx4 acc0 = floatx4{0.f, 0.f, 0.f, 0.f};                               \
    floatx4 acc1 = acc0, acc2 = acc0, acc3 = acc0;                            \
    _Pragma("unroll")                                                         \
    for (int ks = 0; ks < 8; ++ks) {                                          \
      BFrag a0, a1, a2, a3;                                                   \
      a0.v = AF[((((C) * 4 + 0) * 8 + ks) << 6) + lane];                      \
      a1.v = AF[((((C) * 4 + 1) * 8 + ks) << 6) + lane];                      \
      a2.v = AF[((((C) * 4 + 2) * 8 + ks) << 6) + lane];                      \
      a3.v = AF[((((C) * 4 + 3) * 8 + ks) << 6) + lane];                      \
      acc0 = __builtin_amdgcn_mfma_f32_16x16x32_bf16(a0.bf, bfr[ks].bf, acc0, 0, 0, 0); \
      acc1 = __builtin_amdgcn_mfma_f32_16x16x32_bf16(a1.bf, bfr[ks].bf, acc1, 0, 0, 0); \
      acc2 = __builtin_amdgcn_mfma_f32_16x16x32_bf16(a2.bf, bfr[ks].bf, acc2, 0, 0, 0); \
      acc3 = __builtin_amdgcn_mfma_f32_16x16x32_bf16(a3.bf, bfr[ks].bf, acc3, 0, 0, 0); \
    }                                                                         \
    _Pragma("unroll")                                                         \
    for (int mt = 0; mt < 4; ++mt) {                                          \
      const int4 lb = (LB)[mt];                                               \
      const floatx4 a = (mt == 0) ? acc0 : (mt == 1) ? acc1 : (mt == 2) ? acc2 : acc3; \
      _Pragma("unroll")                                                       \
      for (int r = 0; r < 4; ++r) {                                           \
        const unsigned int y = (unsigned int)((r == 0) ? lb.x : (r == 1) ? lb.y : (r == 2) ? lb.z : lb.w); \
        const float x = __uint_as_float(__float_as_uint(a[r]) ^ (y << 31));   \
        const float e = exp2f(x);                                             \
        nn += y ? 0.0f : e;                                                   \
        pp += y ? e : 0.0f;                                                   \
      }                                                                       \
    }                                                                         \
  } while (0)

#pragma unroll 1
  for (int t = 0; t < 8; ++t) {
    // ---- pack this tile's B-fragments (waits tile-t feats, counted vmcnt) ----
    BFrag bfr[8];
#pragma unroll
    for (int ks = 0; ks < 4; ++ks)
#pragma unroll
      for (int jj = 0; jj < 4; ++jj)
        bfr[ks].u32[jj] = pack_bf2(FA[ks * 8 + 2 * jj], FA[ks * 8 + 2 * jj + 1]);
#pragma unroll
    for (int ks = 0; ks < 4; ++ks)
#pragma unroll
      for (int jj = 0; jj < 4; ++jj)
        bfr[4 + ks].u32[jj] = pack_bf2(FB[ks * 8 + 2 * jj], FB[ks * 8 + 2 * jj + 1]);

    const int p1 = wave_px + ((t + 1) << 4);
    const float* fb1 = feats + ((size_t)(p1 >> 14) << 22) + (p1 & 16383) + s;
    const int* lp = labels + (((size_t)(wave_px + (t << 4)) + s) << 8) + (qd << 2);
    const int* lp1 = labels + (((size_t)p1 + s) << 8) + (qd << 2);

    // issue next tile's first feats half (in flight across this tile's compute)
    if (t < 7) {
#pragma unroll
      for (int i = 0; i < 32; ++i) {
        const int k = ((i >> 3) << 5) + (qd << 3) + (i & 7);
        FA[i] = fb1[(size_t)k << 14];
      }
    }
    // labels for chunk1
#pragma unroll
    for (int mt = 0; mt < 4; ++mt)
      lab1[mt] = *(const int4*)(lp + 64 + (mt << 4));

    float nn = 0.0f, pp = 0.0f;

    DO_CHUNK(0, labP);
#pragma unroll
    for (int mt = 0; mt < 4; ++mt)
      lab2[mt] = *(const int4*)(lp + 128 + (mt << 4));

    DO_CHUNK(1, lab1);
#pragma unroll
    for (int mt = 0; mt < 4; ++mt)
      lab3[mt] = *(const int4*)(lp + 192 + (mt << 4));

    DO_CHUNK(2, lab2);
    // issue next tile's second feats half + its chunk0 labels
    if (t < 7) {
#pragma unroll
      for (int i = 0; i < 32; ++i) {
        const int k = 128 + ((i >> 3) << 5) + (qd << 3) + (i & 7);
        FB[i] = fb1[(size_t)k << 14];
      }
#pragma unroll
      for (int mt = 0; mt < 4; ++mt)
        labP[mt] = *(const int4*)(lp1 + (mt << 4));
    }

    DO_CHUNK(3, lab3);

    // ---- per-tile pixel finalize: sum over qd (lanes l, l^16, l^32, l^48) ----
    float sn = nn;
    sn += __shfl_xor(sn, 16);
    sn += __shfl_xor(sn, 32);
    float sp = pp;
    sp += __shfl_xor(sp, 16);
    sp += __shfl_xor(sp, 32);
    if (lane < 16) {
      const float lg = logf(sn * sp + 1.0f);
      loss_acc += lg;
      cnt_acc += (lg != 0.0f) ? 1.0f : 0.0f;
    }
  }
#undef DO_CHUNK

  // ---- wave reduce + one atomic pair per wave ----
#pragma unroll
  for (int off = 1; off < 64; off <<= 1) {
    loss_acc += __shfl_xor(loss_acc, off);
    cnt_acc += __shfl_xor(cnt_acc, off);
  }
  if (lane == 0) {
    atomicAdd(&accum[0], loss_acc);
    atomicAdd(&accum[1], cnt_acc);
  }
}

// ---------------------------------------------------------------------------
// k2: scalar finalize. Mirrors where(lb_num==0, 0, sum/max(lb_num,1)).
// ---------------------------------------------------------------------------
__global__ void pcl_finalize(const float* __restrict__ accum,
                             float* __restrict__ out) {
  const float ssum = accum[0];
  const float c = accum[1];
  out[0] = (c != 0.0f) ? (ssum / c) : 0.0f;
}

extern "C" void kernel_launch(void* const* d_in, const int* in_sizes, int n_in,
                              void* d_out, int out_size, void* d_ws, size_t ws_size,
                              hipStream_t stream) {
  (void)in_sizes; (void)n_in; (void)out_size; (void)ws_size;
  const float* feats = (const float*)d_in[0];
  const float* queue = (const float*)d_in[1];
  const int* labels = (const int*)d_in[2];

  // workspace: [0,128KB) swizzled bf16 queue, [128KB, 128KB+8B) accumulators
  unsigned short* qs = (unsigned short*)d_ws;
  float* accum = (float*)((char*)d_ws + 256 * 256 * sizeof(unsigned short));

  qprep<<<32, 256, 0, stream>>>(queue, qs, accum);
  pcl_main<<<256, 512, 0, stream>>>(feats, labels, qs, accum);
  pcl_finalize<<<1, 1, 0, stream>>>(accum, (float*)d_out);
}

// Round 4
// 586.562 us; speedup vs baseline: 5.3334x; 5.3334x over previous
//
#include <hip/hip_runtime.h>
#include <hip/hip_bf16.h>

// PixelContrastLossOnlyNeg on MI355X.
// feats [16,256,128,128] f32, queue [256,256] f32, labels [262144,256] i32 -> scalar f32.
// Fused bf16-MFMA GEMM (N=262144, M=256, K=256) + masked-exp reduction.
// Memory floor: feats 256MB + labels 256MB = 512MB -> ~81us @ 6.3TB/s.
//
// v4: wave-sized independent blocks. v2 showed phase-lockstepped bursts leave
// all pipes <25% busy; v3's fix (persistent streaming) died of register spills
// (WRITE_SIZE 4.5GB) from launch_bounds-capped VGPRs + cross-tile prefetch
// state. v4 keeps v3's verified math but repartitions: 16384 blocks of ONE
// wave (64 thr), each owning 16 pixels x all 256 classes. B-frags lane-private
// (64 feats dwords -> pack in-reg), A-frags from L2-hot swizzled qs (128KB),
// softmax finishes in-wave. Zero LDS, zero barriers, no prefetch registers ->
// ~120 live VGPRs, 12-16 independent waves/CU at decorrelated phases =
// continuous memory stream. Atomics spread over 64 bins.

typedef __bf16 bf16x8 __attribute__((ext_vector_type(8)));
typedef float floatx4 __attribute__((ext_vector_type(4)));

union BFrag {
  unsigned int u32[4];
  uint4 v;
  bf16x8 bf;
};

// Pack two f32 -> two bf16 (round-half-up; bias ~2^-17 rel, irrelevant here).
__device__ __forceinline__ unsigned int pack_bf2(float a, float b) {
  unsigned int ua = __float_as_uint(a) + 0x8000u;
  unsigned int ub = __float_as_uint(b) + 0x8000u;
  return (ua >> 16) | (ub & 0xffff0000u);
}

// ---------------------------------------------------------------------------
// k0: queue f32 -> bf16 * (log2e/T), stored pre-swizzled in A-fragment lane
// order: tile t = m16*8 + ks, lane L holds A[m=m16*16+(L&15)][k=ks*32+(L>>4)*8+j],
// j=0..7 -> 16B at (t*64+L)*16. Folding log2(e) puts MFMA output in exp2
// domain: exp(logit/T) == exp2(acc). Also zeroes the 64 accumulator bins.
// ---------------------------------------------------------------------------
__global__ void qprep(const float* __restrict__ queue,
                      unsigned short* __restrict__ qs,
                      float* __restrict__ accum) {
  const int gt = blockIdx.x * 256 + threadIdx.x;  // 0..8191
  const int t = gt >> 6;
  const int lane = gt & 63;
  const int m = ((t >> 3) << 4) | (lane & 15);
  const int k0 = ((t & 7) << 5) | ((lane >> 4) << 3);
  const float* qr = queue + m * 256 + k0;
  const float SCALE = 20.6099291556f;  // (1/0.07) * log2(e) folded into Q
  BFrag u;
#pragma unroll
  for (int j = 0; j < 4; ++j)
    u.u32[j] = pack_bf2(qr[2 * j] * SCALE, qr[2 * j + 1] * SCALE);
  *(uint4*)(qs + (size_t)gt * 8) = u.v;
  if (gt < 128) accum[gt] = 0.0f;
}

// ---------------------------------------------------------------------------
// k1: main kernel. One wave per block, 16384 blocks. Block bx owns pixels
// [bx*16, bx*16+16). Lane (qd,s): loads feats column dwords for pixel
// px0+s at k = 8*qd + {0..7} (+32*ks'), packs to 8 bf16x8 B-frags; 4 class
// chunks of 64: 8 ks x {4 A-frag dwordx4 loads from qs (L2-hot), 4 MFMA};
// epilogue in exp2 domain, labels prefetched one chunk ahead. No LDS/barriers.
// ---------------------------------------------------------------------------
__global__ __launch_bounds__(64, 3) void pcl_main(
    const float* __restrict__ feats,
    const int* __restrict__ labels,
    const unsigned short* __restrict__ qs,
    float* __restrict__ accum) {
  const int bx = blockIdx.x;
  const int lane = threadIdx.x & 63;
  const int qd = lane >> 4;   // quad 0..3
  const int s = lane & 15;

  const int px0 = bx << 4;                 // 16 pixels per wave, never crosses batch
  const float* fb = feats + ((size_t)(px0 >> 14) << 22) + (px0 & 16383) + s;
  const int* lp = labels + (((size_t)px0 + s) << 8) + (qd << 2);

  // ---- load 64 feats dwords (k-columns for this lane's pixel) ----
  float FA[32], FB[32];
#pragma unroll
  for (int i = 0; i < 32; ++i) {  // ks 0..3: k = 32*(i>>3) + 8*qd + (i&7)
    const int k = ((i >> 3) << 5) + (qd << 3) + (i & 7);
    FA[i] = fb[(size_t)k << 14];
  }
#pragma unroll
  for (int i = 0; i < 32; ++i) {  // ks 4..7
    const int k = 128 + ((i >> 3) << 5) + (qd << 3) + (i & 7);
    FB[i] = fb[(size_t)k << 14];
  }
  int4 labP[4], lab1[4], lab2[4], lab3[4];
#pragma unroll
  for (int mt = 0; mt < 4; ++mt)
    labP[mt] = *(const int4*)(lp + (mt << 4));

  // ---- pack to bf16 B-fragments (compiler inserts counted vmcnt waits) ----
  BFrag bfr[8];
#pragma unroll
  for (int ks = 0; ks < 4; ++ks)
#pragma unroll
    for (int jj = 0; jj < 4; ++jj)
      bfr[ks].u32[jj] = pack_bf2(FA[ks * 8 + 2 * jj], FA[ks * 8 + 2 * jj + 1]);
#pragma unroll
  for (int ks = 0; ks < 4; ++ks)
#pragma unroll
    for (int jj = 0; jj < 4; ++jj)
      bfr[4 + ks].u32[jj] = pack_bf2(FB[ks * 8 + 2 * jj], FB[ks * 8 + 2 * jj + 1]);

  const uint4* qsv = (const uint4*)qs;
  float nn = 0.0f, pp = 0.0f;

  // chunk C: classes [C*64, C*64+64); LB = labels for this chunk.
#define DO_CHUNK(C, LB)                                                       \
  do {                                                                        \
    floatx4 acc0 = floatx4{0.f, 0.f, 0.f, 0.f};                               \
    floatx4 acc1 = acc0, acc2 = acc0, acc3 = acc0;                            \
    _Pragma("unroll")                                                         \
    for (int ks = 0; ks < 8; ++ks) {                                          \
      BFrag a0, a1, a2, a3;                                                   \
      a0.v = qsv[((((C) * 4 + 0) * 8 + ks) << 6) + lane];                     \
      a1.v = qsv[((((C) * 4 + 1) * 8 + ks) << 6) + lane];                     \
      a2.v = qsv[((((C) * 4 + 2) * 8 + ks) << 6) + lane];                     \
      a3.v = qsv[((((C) * 4 + 3) * 8 + ks) << 6) + lane];                     \
      acc0 = __builtin_amdgcn_mfma_f32_16x16x32_bf16(a0.bf, bfr[ks].bf, acc0, 0, 0, 0); \
      acc1 = __builtin_amdgcn_mfma_f32_16x16x32_bf16(a1.bf, bfr[ks].bf, acc1, 0, 0, 0); \
      acc2 = __builtin_amdgcn_mfma_f32_16x16x32_bf16(a2.bf, bfr[ks].bf, acc2, 0, 0, 0); \
      acc3 = __builtin_amdgcn_mfma_f32_16x16x32_bf16(a3.bf, bfr[ks].bf, acc3, 0, 0, 0); \
    }                                                                         \
    _Pragma("unroll")                                                         \
    for (int mt = 0; mt < 4; ++mt) {                                          \
      const int4 lb = (LB)[mt];                                               \
      const floatx4 a = (mt == 0) ? acc0 : (mt == 1) ? acc1 : (mt == 2) ? acc2 : acc3; \
      _Pragma("unroll")                                                       \
      for (int r = 0; r < 4; ++r) {                                           \
        const unsigned int y = (unsigned int)((r == 0) ? lb.x : (r == 1) ? lb.y : (r == 2) ? lb.z : lb.w); \
        const float x = __uint_as_float(__float_as_uint(a[r]) ^ (y << 31));   \
        const float e = exp2f(x);                                             \
        nn += y ? 0.0f : e;                                                   \
        pp += y ? e : 0.0f;                                                   \
      }                                                                       \
    }                                                                         \
  } while (0)

#pragma unroll
  for (int mt = 0; mt < 4; ++mt)
    lab1[mt] = *(const int4*)(lp + 64 + (mt << 4));
  DO_CHUNK(0, labP);

#pragma unroll
  for (int mt = 0; mt < 4; ++mt)
    lab2[mt] = *(const int4*)(lp + 128 + (mt << 4));
  DO_CHUNK(1, lab1);

#pragma unroll
  for (int mt = 0; mt < 4; ++mt)
    lab3[mt] = *(const int4*)(lp + 192 + (mt << 4));
  DO_CHUNK(2, lab2);

  DO_CHUNK(3, lab3);
#undef DO_CHUNK

  // ---- per-pixel finalize: sum over qd (lanes l, l^16, l^32, l^48) ----
  float sn = nn;
  sn += __shfl_xor(sn, 16);
  sn += __shfl_xor(sn, 32);
  float sp = pp;
  sp += __shfl_xor(sp, 16);
  sp += __shfl_xor(sp, 32);

  float loss_acc = 0.0f, cnt_acc = 0.0f;
  if (lane < 16) {
    const float lg = logf(sn * sp + 1.0f);
    loss_acc = lg;
    cnt_acc = (lg != 0.0f) ? 1.0f : 0.0f;
  }
#pragma unroll
  for (int off = 1; off < 64; off <<= 1) {
    loss_acc += __shfl_xor(loss_acc, off);
    cnt_acc += __shfl_xor(cnt_acc, off);
  }
  if (lane == 0) {
    const int bin = bx & 63;
    atomicAdd(&accum[2 * bin], loss_acc);
    atomicAdd(&accum[2 * bin + 1], cnt_acc);
  }
}

// ---------------------------------------------------------------------------
// k2: finalize. Sums the 64 bins; mirrors where(lb_num==0, 0, sum/max(lb_num,1)).
// ---------------------------------------------------------------------------
__global__ __launch_bounds__(64) void pcl_finalize(const float* __restrict__ accum,
                                                   float* __restrict__ out) {
  const int lane = threadIdx.x & 63;
  float ssum = accum[2 * lane];
  float c = accum[2 * lane + 1];
#pragma unroll
  for (int off = 1; off < 64; off <<= 1) {
    ssum += __shfl_xor(ssum, off);
    c += __shfl_xor(c, off);
  }
  if (lane == 0) out[0] = (c != 0.0f) ? (ssum / c) : 0.0f;
}

extern "C" void kernel_launch(void* const* d_in, const int* in_sizes, int n_in,
                              void* d_out, int out_size, void* d_ws, size_t ws_size,
                              hipStream_t stream) {
  (void)in_sizes; (void)n_in; (void)out_size; (void)ws_size;
  const float* feats = (const float*)d_in[0];
  const float* queue = (const float*)d_in[1];
  const int* labels = (const int*)d_in[2];

  // workspace: [0,128KB) swizzled bf16 queue, [128KB, +512B) accumulator bins
  unsigned short* qs = (unsigned short*)d_ws;
  float* accum = (float*)((char*)d_ws + 256 * 256 * sizeof(unsigned short));

  qprep<<<32, 256, 0, stream>>>(queue, qs, accum);
  pcl_main<<<16384, 64, 0, stream>>>(feats, labels, qs, accum);
  pcl_finalize<<<1, 64, 0, stream>>>(accum, (float*)d_out);
}

// Round 5
// 568.570 us; speedup vs baseline: 5.5022x; 1.0316x over previous
//
#include <hip/hip_runtime.h>
#include <hip/hip_bf16.h>

// PixelContrastLossOnlyNeg on MI355X.
// feats [16,256,128,128] f32, queue [256,256] f32, labels [262144,256] i32 -> scalar f32.
// Fused bf16-MFMA GEMM (N=262144, M=256, K=256) + masked-exp reduction.
// Memory floor: feats 256MB + labels 256MB = 512MB -> ~81us @ 6.3TB/s.
//
// v5: v4 was latency-serialized: VGPR_Count=64 proved the compiler sank every
// load next to its use (zero MLP -> 108k cycles/wave ~= serial latency sum),
// and 1-wave blocks capped residency at 16 wg/CU. v5: (a) 4-wave blocks of
// independent waves (dispatch cap lifted, occupancy VGPR-bound), (b) explicit
// load batching with asm "+v" pins: all 64 feats dwords + 8 label int4s in
// flight before the single counted wait, labels for chunks 2-3 issued during
// chunk-0 compute (vmcnt FIFO drains them before chunk-2). Target <=128 VGPR
// -> 16 waves/CU, each with a full 32KB burst outstanding -> HBM-bound.

typedef __bf16 bf16x8 __attribute__((ext_vector_type(8)));
typedef float floatx4 __attribute__((ext_vector_type(4)));

union BFrag {
  unsigned int u32[4];
  uint4 v;
  bf16x8 bf;
};

// Pack two f32 -> two bf16 (round-half-up; bias ~2^-17 rel, irrelevant here).
__device__ __forceinline__ unsigned int pack_bf2(float a, float b) {
  unsigned int ua = __float_as_uint(a) + 0x8000u;
  unsigned int ub = __float_as_uint(b) + 0x8000u;
  return (ua >> 16) | (ub & 0xffff0000u);
}

// ---------------------------------------------------------------------------
// k0: queue f32 -> bf16 * (log2e/T), stored pre-swizzled in A-fragment lane
// order: tile t = m16*8 + ks, lane L holds A[m=m16*16+(L&15)][k=ks*32+(L>>4)*8+j],
// j=0..7 -> 16B at (t*64+L)*16. Folding log2(e) puts MFMA output in exp2
// domain: exp(logit/T) == exp2(acc). Also zeroes the 64 accumulator bins.
// ---------------------------------------------------------------------------
__global__ void qprep(const float* __restrict__ queue,
                      unsigned short* __restrict__ qs,
                      float* __restrict__ accum) {
  const int gt = blockIdx.x * 256 + threadIdx.x;  // 0..8191
  const int t = gt >> 6;
  const int lane = gt & 63;
  const int m = ((t >> 3) << 4) | (lane & 15);
  const int k0 = ((t & 7) << 5) | ((lane >> 4) << 3);
  const float* qr = queue + m * 256 + k0;
  const float SCALE = 20.6099291556f;  // (1/0.07) * log2(e) folded into Q
  BFrag u;
#pragma unroll
  for (int j = 0; j < 4; ++j)
    u.u32[j] = pack_bf2(qr[2 * j] * SCALE, qr[2 * j + 1] * SCALE);
  *(uint4*)(qs + (size_t)gt * 8) = u.v;
  if (gt < 128) accum[gt] = 0.0f;
}

// ---------------------------------------------------------------------------
// k1: main kernel. 4096 blocks x 256 threads; the 4 waves are fully
// independent (no LDS, no barriers). Wave (bx,w) owns 16 pixels
// px0 = (bx*4+w)*16 and all 256 classes. Lane (qd,s): feats k-column dwords
// for pixel px0+s -> pack to 8 bf16x8 B-frags; 4 class chunks of 64:
// 8 ks x {4 A-frag dwordx4 from L2-hot qs, 4 MFMA}; exp2-domain epilogue.
// ---------------------------------------------------------------------------
__global__ __launch_bounds__(256, 1) void pcl_main(
    const float* __restrict__ feats,
    const int* __restrict__ labels,
    const unsigned short* __restrict__ qs,
    float* __restrict__ accum) {
  const int tid = threadIdx.x;
  const int w = tid >> 6;
  const int lane = tid & 63;
  const int qd = lane >> 4;   // quad 0..3
  const int s = lane & 15;

  const int wid = (blockIdx.x << 2) | w;   // global wave id 0..16383
  const int px0 = wid << 4;                // 16 pixels, never crosses batch
  const float* fb = feats + ((size_t)(px0 >> 14) << 22) + (px0 & 16383) + s;
  const int* lp = labels + (((size_t)px0 + s) << 8) + (qd << 2);

  // ---- issue ALL feats loads (64 dwords/lane) + labels chunks 0-1 ----
  float FA[32], FB[32];
#pragma unroll
  for (int i = 0; i < 32; ++i) {  // ks 0..3: k = 32*(i>>3) + 8*qd + (i&7)
    const int k = ((i >> 3) << 5) + (qd << 3) + (i & 7);
    FA[i] = fb[(size_t)k << 14];
  }
#pragma unroll
  for (int i = 0; i < 32; ++i) {  // ks 4..7
    const int k = 128 + ((i >> 3) << 5) + (qd << 3) + (i & 7);
    FB[i] = fb[(size_t)k << 14];
  }
  int4 LAB01[8];
#pragma unroll
  for (int mt = 0; mt < 8; ++mt)
    LAB01[mt] = *(const int4*)(lp + (mt << 4));

  // ---- pin feats: forces all 64 loads issued before one counted wait ----
#pragma unroll
  for (int i = 0; i < 32; ++i) asm volatile("" : "+v"(FA[i]));
#pragma unroll
  for (int i = 0; i < 32; ++i) asm volatile("" : "+v"(FB[i]));

  // ---- pack to bf16 B-fragments (labels still in flight past this) ----
  BFrag bfr[8];
#pragma unroll
  for (int ks = 0; ks < 4; ++ks)
#pragma unroll
    for (int jj = 0; jj < 4; ++jj)
      bfr[ks].u32[jj] = pack_bf2(FA[ks * 8 + 2 * jj], FA[ks * 8 + 2 * jj + 1]);
#pragma unroll
  for (int ks = 0; ks < 4; ++ks)
#pragma unroll
    for (int jj = 0; jj < 4; ++jj)
      bfr[4 + ks].u32[jj] = pack_bf2(FB[ks * 8 + 2 * jj], FB[ks * 8 + 2 * jj + 1]);

  const uint4* qsv = (const uint4*)qs;
  float nn = 0.0f, pp = 0.0f;

  // chunk C: classes [C*64, C*64+64); labels ARR[B+mt], constant indices.
#define DO_CHUNK(C, ARR, B)                                                   \
  do {                                                                        \
    floatx4 acc0 = floatx4{0.f, 0.f, 0.f, 0.f};                               \
    floatx4 acc1 = acc0, acc2 = acc0, acc3 = acc0;                            \
    _Pragma("unroll")                                                         \
    for (int ks = 0; ks < 8; ++ks) {                                          \
      BFrag a0, a1, a2, a3;                                                   \
      a0.v = qsv[((((C) * 4 + 0) * 8 + ks) << 6) + lane];                     \
      a1.v = qsv[((((C) * 4 + 1) * 8 + ks) << 6) + lane];                     \
      a2.v = qsv[((((C) * 4 + 2) * 8 + ks) << 6) + lane];                     \
      a3.v = qsv[((((C) * 4 + 3) * 8 + ks) << 6) + lane];                     \
      acc0 = __builtin_amdgcn_mfma_f32_16x16x32_bf16(a0.bf, bfr[ks].bf, acc0, 0, 0, 0); \
      acc1 = __builtin_amdgcn_mfma_f32_16x16x32_bf16(a1.bf, bfr[ks].bf, acc1, 0, 0, 0); \
      acc2 = __builtin_amdgcn_mfma_f32_16x16x32_bf16(a2.bf, bfr[ks].bf, acc2, 0, 0, 0); \
      acc3 = __builtin_amdgcn_mfma_f32_16x16x32_bf16(a3.bf, bfr[ks].bf, acc3, 0, 0, 0); \
    }                                                                         \
    _Pragma("unroll")                                                         \
    for (int mt = 0; mt < 4; ++mt) {                                          \
      const int4 lb = (ARR)[(B) + mt];                                        \
      const floatx4 a = (mt == 0) ? acc0 : (mt == 1) ? acc1 : (mt == 2) ? acc2 : acc3; \
      _Pragma("unroll")                                                       \
      for (int r = 0; r < 4; ++r) {                                           \
        const unsigned int y = (unsigned int)((r == 0) ? lb.x : (r == 1) ? lb.y : (r == 2) ? lb.z : lb.w); \
        const float x = __uint_as_float(__float_as_uint(a[r]) ^ (y << 31));   \
        const float e = exp2f(x);                                             \
        nn += y ? 0.0f : e;                                                   \
        pp += y ? e : 0.0f;                                                   \
      }                                                                       \
    }                                                                         \
  } while (0)

  DO_CHUNK(0, LAB01, 0);

  // issue labels for chunks 2-3; FIFO drains them before chunk-2's qs waits
  int4 LAB23[8];
#pragma unroll
  for (int mt = 0; mt < 8; ++mt)
    LAB23[mt] = *(const int4*)(lp + 128 + (mt << 4));

  DO_CHUNK(1, LAB01, 4);
  DO_CHUNK(2, LAB23, 0);
  DO_CHUNK(3, LAB23, 4);
#undef DO_CHUNK

  // ---- per-pixel finalize: sum over qd (lanes l, l^16, l^32, l^48) ----
  float sn = nn;
  sn += __shfl_xor(sn, 16);
  sn += __shfl_xor(sn, 32);
  float sp = pp;
  sp += __shfl_xor(sp, 16);
  sp += __shfl_xor(sp, 32);

  float loss_acc = 0.0f, cnt_acc = 0.0f;
  if (lane < 16) {
    const float lg = logf(sn * sp + 1.0f);
    loss_acc = lg;
    cnt_acc = (lg != 0.0f) ? 1.0f : 0.0f;
  }
#pragma unroll
  for (int off = 1; off < 64; off <<= 1) {
    loss_acc += __shfl_xor(loss_acc, off);
    cnt_acc += __shfl_xor(cnt_acc, off);
  }
  if (lane == 0) {
    const int bin = wid & 63;
    atomicAdd(&accum[2 * bin], loss_acc);
    atomicAdd(&accum[2 * bin + 1], cnt_acc);
  }
}

// ---------------------------------------------------------------------------
// k2: finalize. Sums the 64 bins; mirrors where(lb_num==0, 0, sum/max(lb_num,1)).
// ---------------------------------------------------------------------------
__global__ __launch_bounds__(64) void pcl_finalize(const float* __restrict__ accum,
                                                   float* __restrict__ out) {
  const int lane = threadIdx.x & 63;
  float ssum = accum[2 * lane];
  float c = accum[2 * lane + 1];
#pragma unroll
  for (int off = 1; off < 64; off <<= 1) {
    ssum += __shfl_xor(ssum, off);
    c += __shfl_xor(c, off);
  }
  if (lane == 0) out[0] = (c != 0.0f) ? (ssum / c) : 0.0f;
}

extern "C" void kernel_launch(void* const* d_in, const int* in_sizes, int n_in,
                              void* d_out, int out_size, void* d_ws, size_t ws_size,
                              hipStream_t stream) {
  (void)in_sizes; (void)n_in; (void)out_size; (void)ws_size;
  const float* feats = (const float*)d_in[0];
  const float* queue = (const float*)d_in[1];
  const int* labels = (const int*)d_in[2];

  // workspace: [0,128KB) swizzled bf16 queue, [128KB, +512B) accumulator bins
  unsigned short* qs = (unsigned short*)d_ws;
  float* accum = (float*)((char*)d_ws + 256 * 256 * sizeof(unsigned short));

  qprep<<<32, 256, 0, stream>>>(queue, qs, accum);
  pcl_main<<<4096, 256, 0, stream>>>(feats, labels, qs, accum);
  pcl_finalize<<<1, 64, 0, stream>>>(accum, (float*)d_out);
}